// Round 4
// baseline (506.845 us; speedup 1.0000x reference)
//
#include <hip/hip_runtime.h>
#include <hip/hip_bf16.h>

typedef float v2f __attribute__((ext_vector_type(2)));

static constexpr int T = 512;
static constexpr int B = 4096;

__device__ __forceinline__ float frcp_(float x) { return __builtin_amdgcn_rcpf(x); }
__device__ __forceinline__ float sig_(float x) { return frcp_(1.0f + __expf(-x)); }
__device__ __forceinline__ float tanh_(float x) { return 1.0f - 2.0f * frcp_(1.0f + __expf(2.0f * x)); }

__device__ __forceinline__ float bperm_(int idx, float v) {
    return __int_as_float(__builtin_amdgcn_ds_bpermute(idx, __float_as_int(v)));
}

// Compiler fence + scheduling barrier. All cross-lane traffic is within one
// wave; same-wave LDS ops complete in order, so no s_waitcnt/s_barrier is
// needed — only compiler reordering must be prevented.
#define WAVE_SYNC() do { asm volatile("" ::: "memory"); \
                         __builtin_amdgcn_wave_barrier(); \
                         asm volatile("" ::: "memory"); } while (0)

// ---------------- Kernel 1: layer-0 backward scan (unchanged, proven) ------
__global__ void __launch_bounds__(256, 1) k_l0_bwd(
    const float* __restrict__ x,      // [B,T]
    const float* __restrict__ Wih,    // [48,1]
    const float* __restrict__ Whh,    // [48,16]
    const float* __restrict__ bih,    // [48]
    const float* __restrict__ bhh,    // [48]
    __hip_bfloat16* __restrict__ y0b) // [T,B,16] bf16
{
    __shared__ float hbuf[256];
    const int tid = threadIdx.x;
    const int g = tid >> 4, j = tid & 15;
    const int b = blockIdx.x * 16 + g;

    v2f wr[8], wz[8], wn[8];
    {
        const v2f* pr = reinterpret_cast<const v2f*>(Whh + j * 16);
        const v2f* pz = reinterpret_cast<const v2f*>(Whh + (16 + j) * 16);
        const v2f* pn = reinterpret_cast<const v2f*>(Whh + (32 + j) * 16);
#pragma unroll
        for (int q = 0; q < 8; ++q) { wr[q] = pr[q]; wz[q] = pz[q]; wn[q] = pn[q]; }
    }
    const float wxr = Wih[j], wxz = Wih[16 + j], wxn = Wih[32 + j];
    const float br   = bih[j] + bhh[j];
    const float bz   = bih[16 + j] + bhh[16 + j];
    const float bin_ = bih[32 + j];
    const float bhn  = bhh[32 + j];

    float hj = 0.0f;
    v2f hv[8];
#pragma unroll
    for (int q = 0; q < 8; ++q) { hv[q][0] = 0.0f; hv[q][1] = 0.0f; }

    const float* xrow = x + (size_t)b * T;
    __hip_bfloat16* yp = y0b + ((size_t)(T - 1) * B + b) * 16 + j;
    float xv = xrow[T - 1];
    for (int t = T - 1; t >= 0; --t) {
        float xn = xrow[(t > 0) ? t - 1 : 0];
        v2f ar0{}, ar1{}, az0{}, az1{}, an0{}, an1{};
#pragma unroll
        for (int q = 0; q < 4; ++q) {
            ar0 += wr[q] * hv[q];
            az0 += wz[q] * hv[q];
            an0 += wn[q] * hv[q];
        }
#pragma unroll
        for (int q = 4; q < 8; ++q) {
            ar1 += wr[q] * hv[q];
            az1 += wz[q] * hv[q];
            an1 += wn[q] * hv[q];
        }
        float ar = (ar0[0] + ar0[1]) + (ar1[0] + ar1[1]) + fmaf(xv, wxr, br);
        float az = (az0[0] + az0[1]) + (az1[0] + az1[1]) + fmaf(xv, wxz, bz);
        float hn = (an0[0] + an0[1]) + (an1[0] + an1[1]) + bhn;
        float ai = fmaf(xv, wxn, bin_);
        float r = sig_(ar), z = sig_(az);
        float n = tanh_(fmaf(r, hn, ai));
        hj = fmaf(z, hj - n, n);
        *yp = __hip_bfloat16(hj);
        yp -= (size_t)B * 16;
        hbuf[tid] = hj;
        WAVE_SYNC();
#pragma unroll
        for (int q = 0; q < 4; ++q) {
            float4 v = *reinterpret_cast<const float4*>(&hbuf[g * 16 + 4 * q]);
            hv[2 * q + 0][0] = v.x; hv[2 * q + 0][1] = v.y;
            hv[2 * q + 1][0] = v.z; hv[2 * q + 1][1] = v.w;
        }
        WAVE_SYNC();
        xv = xn;
    }
}

// ---- Kernel 2: role-decomposed fused L0-fwd + L1-fwd + L1-bwd step -------
// One wave = one sequence. Lanes 0..47 (role 0/1/2 = r/z/n, row m=lane&15):
// own L1 gate-row `lane` ih-part AND L0 gate-row `lane`. Lanes 48..63: L1
// hh-dots for row m. L1 runs one step behind L0 (skewed pipeline): single
// LDS exchange point per iteration. LDS per seq: h0[16]|h1[16]|y0[16]|pad.
__global__ void __launch_bounds__(256, 4) k_fused_role(
    const float* __restrict__ x,
    const float* __restrict__ Wih0, const float* __restrict__ Whh0,
    const float* __restrict__ bih0, const float* __restrict__ bhh0,
    const float* __restrict__ Wih1, const float* __restrict__ Whh1,
    const float* __restrict__ bih1, const float* __restrict__ bhh1,
    const float* __restrict__ Wih1b,
    const float* __restrict__ bih1b, const float* __restrict__ bhh1b,
    const __hip_bfloat16* __restrict__ y0b, // [T,B,16]
    float* __restrict__ out)                 // [B,32]
{
    __shared__ float lds[4 * 64];
    const int tid  = threadIdx.x;
    const int wid  = tid >> 6;
    const int lane = tid & 63;
    const int m    = lane & 15;
    const int role = lane >> 4;          // 0 R, 1 Z, 2 N, 3 HH
    const bool isHH = (role == 3);
    const int b = blockIdx.x * 4 + wid;
    float* sb = lds + wid * 64;

    // per-role weight rows (24 v2f resident)
    const float *p0, *p1, *p2;
    if (!isHH) {
        p0 = Wih1 + lane * 32;           // L1 row `lane`, h0-cols
        p1 = Wih1 + lane * 32 + 16;      // L1 row `lane`, y0-cols
        p2 = Whh0 + lane * 16;           // L0 hh row `lane`
    } else {
        p0 = Whh1 + m * 16;              // L1 hh r-row
        p1 = Whh1 + (16 + m) * 16;       // z-row
        p2 = Whh1 + (32 + m) * 16;       // n-row
    }
    v2f w0[8], w1[8], w2[8];
#pragma unroll
    for (int q = 0; q < 8; ++q) {
        w0[q] = reinterpret_cast<const v2f*>(p0)[q];
        w1[q] = reinterpret_cast<const v2f*>(p1)[q];
        w2[q] = reinterpret_cast<const v2f*>(p2)[q];
    }

    // biases folded into acc inits; x-weights per role
    float a0i, a1i, a2i, wx, wx2, bin2;
    if (!isHH) {
        a0i = bih1[lane]; a1i = 0.0f;
        a2i = (role < 2) ? (bih0[lane] + bhh0[lane]) : bhh0[lane];
        wx  = (role < 2) ? Wih0[lane] : 0.0f;
        wx2 = (role == 2) ? Wih0[lane] : 0.0f;
        bin2 = (role == 2) ? bih0[lane] : 0.0f;
    } else {
        a0i = bhh1[m]; a1i = bhh1[16 + m]; a2i = bhh1[32 + m];
        wx = 0.0f; wx2 = 0.0f; bin2 = 0.0f;
    }

    const float* Abase = sb + (isHH ? 16 : 0);   // h0 or h1
    const float* Bbase = sb + (isHH ? 16 : 32);  // y0 or h1

    sb[lane] = 0.0f;                     // h0(-1)=h1(-2)=0, y0 dummy
    WAVE_SYNC();

    const int idx16 = (lane ^ 16) << 2;
    const int idx32 = (lane ^ 32) << 2;
    const int idx48 = (lane ^ 48) << 2;

    const float* xrow = x + (size_t)b * T;
    float x_cur = xrow[0];
    float x_next = xrow[1];
    const unsigned short* yg = reinterpret_cast<const unsigned short*>(y0b) + (size_t)b * 16 + m;
    unsigned short y_reg = yg[0];        // y0b[t=0][b][m]

    float h0prev = 0.0f, h1prev = 0.0f, h1j = 0.0f;
    v2f A[8], Bv[8];

    for (int it = 0; it <= T; ++it) {
        // ---- exchange reads (h0(t-1)/h1 | y0/h1)
#pragma unroll
        for (int q = 0; q < 4; ++q) {
            float4 va = *reinterpret_cast<const float4*>(Abase + 4 * q);
            float4 vb = *reinterpret_cast<const float4*>(Bbase + 4 * q);
            A[2*q+0][0] = va.x; A[2*q+0][1] = va.y;
            A[2*q+1][0] = va.z; A[2*q+1][1] = va.w;
            Bv[2*q+0][0] = vb.x; Bv[2*q+0][1] = vb.y;
            Bv[2*q+1][0] = vb.z; Bv[2*q+1][1] = vb.w;
        }
        // ---- uniform dot phase
        v2f acc0; acc0[0] = a0i; acc0[1] = 0.0f;
        v2f acc1; acc1[0] = a1i; acc1[1] = 0.0f;
        v2f acc2; acc2[0] = a2i; acc2[1] = 0.0f;
#pragma unroll
        for (int q = 0; q < 8; ++q) {
            acc0 += w0[q] * A[q];
            acc1 += w1[q] * Bv[q];
            acc2 += w2[q] * A[q];
        }
        float s0 = acc0[0] + acc0[1];
        float s1 = acc1[0] + acc1[1];
        float s2 = acc2[0] + acc2[1];
        float ih  = s0 + s1;                    // L1 ih pre (lanes<48)
        float pre = fmaf(x_cur, wx, s2);        // L0 pre (r/z) | h_n0 (n)
        float inx = fmaf(x_cur, wx2, bin2);     // L0 i_n (n-lanes)
        // ---- phase 1: hh parts to ih lanes
        float t48v = bperm_(idx48, s0);
        float t32v = bperm_(idx32, s1);
        float t16v = bperm_(idx16, s2);
        float hh = (role == 0) ? t48v : (role == 1) ? t32v : t16v;
        float preL1 = ih + hh;
        float e0 = sig_(pre);                   // r0 on R | z0 on Z
        float e1 = sig_(preL1);                 // r1 on R | z1 on Z
        // ---- phase 2: r to N lanes
        float u0 = bperm_(idx32, e0);
        float u1 = bperm_(idx32, e1);
        float n0 = tanh_(fmaf(u0, pre, inx));   // valid on N (pre = h_n0)
        float n1 = tanh_(fmaf(u1, hh, ih));     // valid on N (hh = h_n1, ih = i_n1)
        // ---- phase 3: n to Z lanes
        float v0 = bperm_(idx48, n0);
        float v1 = bperm_(idx48, n1);
        float h0n = fmaf(e0, h0prev - v0, v0);  // (1-z)n + z h, on Z
        float h1n = fmaf(e1, h1prev - v1, v1);
        h1n = (it == 0) ? 0.0f : h1n;           // discard L1 warm-up step
        h0prev = h0n; h1prev = h1n; h1j = h1n;
        // ---- publish state + y0(t)
        if (role == 1) { sb[m] = h0n; sb[16 + m] = h1n; }
        if (role == 0) {
            union { unsigned u; float f; } cv; cv.u = ((unsigned)y_reg) << 16;
            sb[32 + m] = cv.f;
        }
        int tn = (it < T - 1) ? it + 1 : T - 1;
        y_reg = yg[(size_t)tn * B * 16];
        x_cur = x_next;
        x_next = xrow[(it < T - 2) ? it + 2 : T - 1];
        WAVE_SYNC();
    }

    // ---- epilogue: L1 backward single step at t=T-1 (h=0).
    // A (lanes<48) = h0(T-1), Bv = y0(T-1) from the it==T reads.
    const int le = (lane < 48) ? lane : 47;     // keep OOB lanes in-bounds
    float bi_b = bih1b[le];
    float hh_b = bhh1b[le];
    const v2f* qb = reinterpret_cast<const v2f*>(Wih1b + le * 32);
    v2f ab0; ab0[0] = bi_b; ab0[1] = 0.0f;
    v2f ab1; ab1[0] = 0.0f; ab1[1] = 0.0f;
#pragma unroll
    for (int q = 0; q < 8; ++q) {
        ab0 += qb[q] * A[q];
        ab1 += qb[8 + q] * Bv[q];
    }
    float sb_ = (ab0[0] + ab0[1]) + (ab1[0] + ab1[1]);
    float eb = sig_(sb_ + hh_b);                // rb on R | zb on Z
    float ub = bperm_(idx32, eb);               // N gets rb
    float nb = tanh_(fmaf(ub, hh_b, sb_));      // N: tanh(i_n + r*h_n)
    float vb = bperm_(idx48, nb);               // Z gets nb
    float h1bv = (1.0f - eb) * vb;              // (1-z)*n + z*0
    if (role == 1) {
        out[(size_t)b * 32 + m]      = h1j;     // forward h1(T-1)
        out[(size_t)b * 32 + 16 + m] = h1bv;    // backward single step
    }
}

extern "C" void kernel_launch(void* const* d_in, const int* in_sizes, int n_in,
                              void* d_out, int out_size, void* d_ws, size_t ws_size,
                              hipStream_t stream) {
    const float* x     = (const float*)d_in[0];
    const float* Wih0f = (const float*)d_in[1];
    const float* Whh0f = (const float*)d_in[2];
    const float* bih0f = (const float*)d_in[3];
    const float* bhh0f = (const float*)d_in[4];
    const float* Wih0b = (const float*)d_in[5];
    const float* Whh0b = (const float*)d_in[6];
    const float* bih0b = (const float*)d_in[7];
    const float* bhh0b = (const float*)d_in[8];
    const float* Wih1f = (const float*)d_in[9];
    const float* Whh1f = (const float*)d_in[10];
    const float* bih1f = (const float*)d_in[11];
    const float* bhh1f = (const float*)d_in[12];
    const float* Wih1b = (const float*)d_in[13];
    const float* bih1b = (const float*)d_in[15];
    const float* bhh1b = (const float*)d_in[16];
    __hip_bfloat16* y0b = (__hip_bfloat16*)d_ws;   // [T,B,16] bf16 = 64 MiB
    float* out = (float*)d_out;

    hipLaunchKernelGGL(k_l0_bwd, dim3(B / 16), dim3(256), 0, stream,
                       x, Wih0b, Whh0b, bih0b, bhh0b, y0b);
    hipLaunchKernelGGL(k_fused_role, dim3(B / 4), dim3(256), 0, stream,
                       x, Wih0f, Whh0f, bih0f, bhh0f,
                       Wih1f, Whh1f, bih1f, bhh1f,
                       Wih1b, bih1b, bhh1b,
                       y0b, out);
}

// Round 5
// 426.393 us; speedup vs baseline: 1.1887x; 1.1887x over previous
//
#include <hip/hip_runtime.h>
#include <hip/hip_bf16.h>

typedef float v2f __attribute__((ext_vector_type(2)));

static constexpr int T = 512;
static constexpr int B = 4096;

__device__ __forceinline__ float frcp_(float x) { return __builtin_amdgcn_rcpf(x); }
__device__ __forceinline__ float sig_(float x) { return frcp_(1.0f + __expf(-x)); }
__device__ __forceinline__ float tanh_(float x) { return 1.0f - 2.0f * frcp_(1.0f + __expf(2.0f * x)); }

// xor-16 butterfly within 32-lane group: BitMode offset = (16<<10)|0x1F
__device__ __forceinline__ float swz16_(float v) {
    return __int_as_float(__builtin_amdgcn_ds_swizzle(__float_as_int(v), 0x401F));
}

// Compiler fence + scheduling barrier. All cross-lane traffic (LDS slots,
// swizzles) stays within one wave; same-wave LDS ops complete in order in HW,
// so no s_waitcnt/s_barrier is needed — only compiler reordering must be
// prevented.
#define WAVE_SYNC() do { asm volatile("" ::: "memory"); \
                         __builtin_amdgcn_wave_barrier(); \
                         asm volatile("" ::: "memory"); } while (0)

// ---------------- Kernel 1: layer-0 backward scan, 32 lanes/seq ------------
// Lane (j, half): rows j,16+j,32+j, k-range [half*8, half*8+8).
__global__ void __launch_bounds__(256, 2) k_l0_bwd(
    const float* __restrict__ x,      // [B,T]
    const float* __restrict__ Wih,    // [48,1]
    const float* __restrict__ Whh,    // [48,16]
    const float* __restrict__ bih,    // [48]
    const float* __restrict__ bhh,    // [48]
    __hip_bfloat16* __restrict__ y0b) // [T,B,16] bf16
{
    __shared__ float hbuf[8 * 16];
    const int tid  = threadIdx.x;
    const int s    = tid >> 5;         // seq slot in block (0..7)
    const int j    = tid & 15;
    const int half = (tid >> 4) & 1;
    const int b    = blockIdx.x * 8 + s;
    float* hb = hbuf + s * 16;

    v2f wr[4], wz[4], wn[4];
    {
        const v2f* pr = reinterpret_cast<const v2f*>(Whh + j * 16 + half * 8);
        const v2f* pz = reinterpret_cast<const v2f*>(Whh + (16 + j) * 16 + half * 8);
        const v2f* pn = reinterpret_cast<const v2f*>(Whh + (32 + j) * 16 + half * 8);
#pragma unroll
        for (int q = 0; q < 4; ++q) { wr[q] = pr[q]; wz[q] = pz[q]; wn[q] = pn[q]; }
    }
    // x-weights & biases: fold into half-0 partial only (avoid double count)
    const float wxr_ = half ? 0.0f : Wih[j];
    const float wxz_ = half ? 0.0f : Wih[16 + j];
    const float br_  = half ? 0.0f : bih[j] + bhh[j];
    const float bz_  = half ? 0.0f : bih[16 + j] + bhh[16 + j];
    const float bhn_ = half ? 0.0f : bhh[32 + j];
    const float wxn  = Wih[32 + j];   // both halves (outside reduced sum)
    const float bin_ = bih[32 + j];

    if (half == 0) hb[j] = 0.0f;
    WAVE_SYNC();

    const float* xrow = x + (size_t)b * T;
    __hip_bfloat16* yp = y0b + ((size_t)(T - 1) * B + b) * 16 + j;
    float xv = xrow[T - 1];
    float hj = 0.0f;

    for (int t = T - 1; t >= 0; --t) {
        float xn = xrow[(t > 0) ? t - 1 : 0];     // 1-step prefetch
        v2f A[4];
        {
            float4 v0 = *reinterpret_cast<const float4*>(hb + half * 8);
            float4 v1 = *reinterpret_cast<const float4*>(hb + half * 8 + 4);
            A[0][0] = v0.x; A[0][1] = v0.y; A[1][0] = v0.z; A[1][1] = v0.w;
            A[2][0] = v1.x; A[2][1] = v1.y; A[3][0] = v1.z; A[3][1] = v1.w;
        }
        v2f a0 = { fmaf(xv, wxr_, br_), 0.0f };
        v2f a1 = { fmaf(xv, wxz_, bz_), 0.0f };
        v2f a2 = { bhn_, 0.0f };
#pragma unroll
        for (int q = 0; q < 4; ++q) {
            a0 += wr[q] * A[q];
            a1 += wz[q] * A[q];
            a2 += wn[q] * A[q];
        }
        float ar = a0[0] + a0[1];  ar += swz16_(ar);
        float az = a1[0] + a1[1];  az += swz16_(az);
        float hn = a2[0] + a2[1];  hn += swz16_(hn);
        float r = sig_(ar), z = sig_(az);
        float n = tanh_(fmaf(r, hn, fmaf(xv, wxn, bin_)));
        hj = fmaf(z, hj - n, n);
        if (half == 0) {
            *yp = __hip_bfloat16(hj);
            hb[j] = hj;            // depends on this iter's reads -> ordered
        }
        yp -= (size_t)B * 16;
        WAVE_SYNC();
        xv = xn;
    }
}

// ---- Kernel 2: fused L0-fwd + L1-fwd (skewed) + L1-bwd step, 32 lanes/seq -
// LDS per seq: h0[0:16) h1[16:32) y0[32:48).
// Body iteration it: L0 step it (h0(it)), L1 step it-1 (h1(it-1)).
__global__ void __launch_bounds__(256, 2) k_fused(
    const float* __restrict__ x,
    const float* __restrict__ Wih0, const float* __restrict__ Whh0,
    const float* __restrict__ bih0, const float* __restrict__ bhh0,
    const float* __restrict__ Wih1, const float* __restrict__ Whh1,
    const float* __restrict__ bih1, const float* __restrict__ bhh1,
    const float* __restrict__ Wih1b,
    const float* __restrict__ bih1b, const float* __restrict__ bhh1b,
    const __hip_bfloat16* __restrict__ y0b, // [T,B,16]
    float* __restrict__ out)                 // [B,32]
{
    __shared__ float lds[8 * 48];
    const int tid  = threadIdx.x;
    const int s    = tid >> 5;
    const int j    = tid & 15;
    const int half = (tid >> 4) & 1;
    const int b    = blockIdx.x * 8 + s;
    float* sb = lds + s * 48;

    // L0 hh weights, half slice [half*8, +8)
    v2f w0r[4], w0z[4], w0n[4];
    {
        const v2f* pr = reinterpret_cast<const v2f*>(Whh0 + j * 16 + half * 8);
        const v2f* pz = reinterpret_cast<const v2f*>(Whh0 + (16 + j) * 16 + half * 8);
        const v2f* pn = reinterpret_cast<const v2f*>(Whh0 + (32 + j) * 16 + half * 8);
#pragma unroll
        for (int q = 0; q < 4; ++q) { w0r[q] = pr[q]; w0z[q] = pz[q]; w0n[q] = pn[q]; }
    }
    // L1 ih weights over 32-wide input, half slice [half*16, +16)
    v2f w1r[8], w1z[8], w1n[8];
    {
        const v2f* pr = reinterpret_cast<const v2f*>(Wih1 + j * 32 + half * 16);
        const v2f* pz = reinterpret_cast<const v2f*>(Wih1 + (16 + j) * 32 + half * 16);
        const v2f* pn = reinterpret_cast<const v2f*>(Wih1 + (32 + j) * 32 + half * 16);
#pragma unroll
        for (int q = 0; q < 8; ++q) { w1r[q] = pr[q]; w1z[q] = pz[q]; w1n[q] = pn[q]; }
    }
    // L1 hh weights, half slice
    v2f u1r[4], u1z[4], u1n[4];
    {
        const v2f* pr = reinterpret_cast<const v2f*>(Whh1 + j * 16 + half * 8);
        const v2f* pz = reinterpret_cast<const v2f*>(Whh1 + (16 + j) * 16 + half * 8);
        const v2f* pn = reinterpret_cast<const v2f*>(Whh1 + (32 + j) * 16 + half * 8);
#pragma unroll
        for (int q = 0; q < 4; ++q) { u1r[q] = pr[q]; u1z[q] = pz[q]; u1n[q] = pn[q]; }
    }
    // biases / x-weights (reduced sums carry them on half 0 only)
    const float wx0r_ = half ? 0.0f : Wih0[j];
    const float wx0z_ = half ? 0.0f : Wih0[16 + j];
    const float b0r_  = half ? 0.0f : bih0[j] + bhh0[j];
    const float b0z_  = half ? 0.0f : bih0[16 + j] + bhh0[16 + j];
    const float b0hn_ = half ? 0.0f : bhh0[32 + j];
    const float wx0n  = Wih0[32 + j];
    const float b0in  = bih0[32 + j];
    const float b1r_  = half ? 0.0f : bih1[j] + bhh1[j];
    const float b1z_  = half ? 0.0f : bih1[16 + j] + bhh1[16 + j];
    const float b1in_ = half ? 0.0f : bih1[32 + j];
    const float b1hn_ = half ? 0.0f : bhh1[32 + j];

    if (half == 0) { sb[j] = 0.0f; sb[16 + j] = 0.0f; sb[32 + j] = 0.0f; }
    WAVE_SYNC();

    const float* xrow = x + (size_t)b * T;
    const unsigned short* yg =
        reinterpret_cast<const unsigned short*>(y0b) + (size_t)b * 16 + j;
    float x_cur = xrow[0];
    unsigned short y_reg = yg[0];     // y0(0); published at end of it=0
    float h0prev = 0.0f, h1prev = 0.0f;

    const float* Ap = sb + half * 8;          // h0 half slice (L0 input)
    const float* Bp = sb + (half ? 32 : 0);   // full h0 (half0) | full y0 (half1)
    const float* Cp = sb + 16 + half * 8;     // h1 half slice

    for (int it = 0; it < T; ++it) {
        const int tn = (it < T - 1) ? it + 1 : T - 1;
        float x_nxt = xrow[tn];                              // prefetch
        unsigned short y_nxt = yg[(size_t)tn * B * 16];      // prefetch

        v2f A[4], Bv[8], C[4];
        {
            float4 v0 = *reinterpret_cast<const float4*>(Ap);
            float4 v1 = *reinterpret_cast<const float4*>(Ap + 4);
            A[0][0] = v0.x; A[0][1] = v0.y; A[1][0] = v0.z; A[1][1] = v0.w;
            A[2][0] = v1.x; A[2][1] = v1.y; A[3][0] = v1.z; A[3][1] = v1.w;
        }
#pragma unroll
        for (int q = 0; q < 4; ++q) {
            float4 v = *reinterpret_cast<const float4*>(Bp + 4 * q);
            Bv[2 * q + 0][0] = v.x; Bv[2 * q + 0][1] = v.y;
            Bv[2 * q + 1][0] = v.z; Bv[2 * q + 1][1] = v.w;
        }
        {
            float4 v0 = *reinterpret_cast<const float4*>(Cp);
            float4 v1 = *reinterpret_cast<const float4*>(Cp + 4);
            C[0][0] = v0.x; C[0][1] = v0.y; C[1][0] = v0.z; C[1][1] = v0.w;
            C[2][0] = v1.x; C[2][1] = v1.y; C[3][0] = v1.z; C[3][1] = v1.w;
        }

        // ---- L0 partials
        v2f a0 = { fmaf(x_cur, wx0r_, b0r_), 0.0f };
        v2f a1 = { fmaf(x_cur, wx0z_, b0z_), 0.0f };
        v2f a2 = { b0hn_, 0.0f };
#pragma unroll
        for (int q = 0; q < 4; ++q) {
            a0 += w0r[q] * A[q];
            a1 += w0z[q] * A[q];
            a2 += w0n[q] * A[q];
        }
        // ---- L1 partials: pre_r/pre_z merged (ih+hh); i_n / h_n separate
        v2f c0 = { b1r_, 0.0f };
        v2f c1 = { b1z_, 0.0f };
        v2f c2 = { b1in_, 0.0f };
        v2f c3 = { b1hn_, 0.0f };
#pragma unroll
        for (int q = 0; q < 8; ++q) {
            c0 += w1r[q] * Bv[q];
            c1 += w1z[q] * Bv[q];
            c2 += w1n[q] * Bv[q];
        }
#pragma unroll
        for (int q = 0; q < 4; ++q) {
            c0 += u1r[q] * C[q];
            c1 += u1z[q] * C[q];
            c3 += u1n[q] * C[q];
        }
        // ---- cross-half reduce (7 swizzle+add)
        float ar  = a0[0] + a0[1];  ar  += swz16_(ar);
        float az  = a1[0] + a1[1];  az  += swz16_(az);
        float hn0 = a2[0] + a2[1];  hn0 += swz16_(hn0);
        float pr  = c0[0] + c0[1];  pr  += swz16_(pr);
        float pz  = c1[0] + c1[1];  pz  += swz16_(pz);
        float i1n = c2[0] + c2[1];  i1n += swz16_(i1n);
        float hn1 = c3[0] + c3[1];  hn1 += swz16_(hn1);

        // ---- L0 nonlinearity (step it)
        float r0 = sig_(ar), z0 = sig_(az);
        float n0 = tanh_(fmaf(r0, hn0, fmaf(x_cur, wx0n, b0in)));
        float h0new = fmaf(z0, h0prev - n0, n0);
        // ---- L1 nonlinearity (step it-1)
        float r1 = sig_(pr), z1 = sig_(pz);
        float n1 = tanh_(fmaf(r1, hn1, i1n));
        float h1new = fmaf(z1, h1prev - n1, n1);
        if (it == 0) h1new = 0.0f;   // discard warm-up step
        h0prev = h0new; h1prev = h1new;

        WAVE_SYNC();                 // WAR fence (y0 publish has no data dep)
        if (half == 0) {
            sb[j] = h0new;
            sb[16 + j] = h1new;
        } else {
            union { unsigned u; float f; } cv;
            cv.u = ((unsigned)y_reg) << 16;
            sb[32 + j] = cv.f;       // y0(it), consumed at it+1
        }
        WAVE_SYNC();
        x_cur = x_nxt; y_reg = y_nxt;
    }

    // ---- final L1 step (it = T-1): h1(T-1) from h1(T-2), h0(T-1), y0(T-1)
    v2f Bv[8], C[4];
#pragma unroll
    for (int q = 0; q < 4; ++q) {
        float4 v = *reinterpret_cast<const float4*>(Bp + 4 * q);
        Bv[2 * q + 0][0] = v.x; Bv[2 * q + 0][1] = v.y;
        Bv[2 * q + 1][0] = v.z; Bv[2 * q + 1][1] = v.w;
    }
    {
        float4 v0 = *reinterpret_cast<const float4*>(Cp);
        float4 v1 = *reinterpret_cast<const float4*>(Cp + 4);
        C[0][0] = v0.x; C[0][1] = v0.y; C[1][0] = v0.z; C[1][1] = v0.w;
        C[2][0] = v1.x; C[2][1] = v1.y; C[3][0] = v1.z; C[3][1] = v1.w;
    }
    v2f c0 = { b1r_, 0.0f };
    v2f c1 = { b1z_, 0.0f };
    v2f c2 = { b1in_, 0.0f };
    v2f c3 = { b1hn_, 0.0f };
#pragma unroll
    for (int q = 0; q < 8; ++q) {
        c0 += w1r[q] * Bv[q];
        c1 += w1z[q] * Bv[q];
        c2 += w1n[q] * Bv[q];
    }
#pragma unroll
    for (int q = 0; q < 4; ++q) {
        c0 += u1r[q] * C[q];
        c1 += u1z[q] * C[q];
        c3 += u1n[q] * C[q];
    }
    float pr  = c0[0] + c0[1];  pr  += swz16_(pr);
    float pz  = c1[0] + c1[1];  pz  += swz16_(pz);
    float i1n = c2[0] + c2[1];  i1n += swz16_(i1n);
    float hn1 = c3[0] + c3[1];  hn1 += swz16_(hn1);
    float r1 = sig_(pr), z1 = sig_(pz);
    float n1 = tanh_(fmaf(r1, hn1, i1n));
    float h1T = fmaf(z1, h1prev - n1, n1);     // h1f(T-1)

    // ---- L1 backward single step at t=T-1 (h=0); input = [h0f(T-1), y0(T-1)]
    {
        const v2f* qr = reinterpret_cast<const v2f*>(Wih1b + j * 32 + half * 16);
        const v2f* qz = reinterpret_cast<const v2f*>(Wih1b + (16 + j) * 32 + half * 16);
        const v2f* qn = reinterpret_cast<const v2f*>(Wih1b + (32 + j) * 32 + half * 16);
        v2f d0 = { half ? 0.0f : bih1b[j] + bhh1b[j], 0.0f };
        v2f d1 = { half ? 0.0f : bih1b[16 + j] + bhh1b[16 + j], 0.0f };
        v2f d2 = { half ? 0.0f : bih1b[32 + j], 0.0f };
#pragma unroll
        for (int q = 0; q < 8; ++q) {
            d0 += qr[q] * Bv[q];
            d1 += qz[q] * Bv[q];
            d2 += qn[q] * Bv[q];
        }
        float gr = d0[0] + d0[1];  gr += swz16_(gr);
        float gz = d1[0] + d1[1];  gz += swz16_(gz);
        float gi = d2[0] + d2[1];  gi += swz16_(gi);
        float rb = sig_(gr), zb = sig_(gz);
        float nb = tanh_(fmaf(rb, bhh1b[32 + j], gi));
        float outb = (1.0f - zb) * nb;
        if (half == 0) {
            out[(size_t)b * 32 + j]      = h1T;
            out[(size_t)b * 32 + 16 + j] = outb;
        }
    }
}

extern "C" void kernel_launch(void* const* d_in, const int* in_sizes, int n_in,
                              void* d_out, int out_size, void* d_ws, size_t ws_size,
                              hipStream_t stream) {
    const float* x     = (const float*)d_in[0];
    const float* Wih0f = (const float*)d_in[1];
    const float* Whh0f = (const float*)d_in[2];
    const float* bih0f = (const float*)d_in[3];
    const float* bhh0f = (const float*)d_in[4];
    const float* Wih0b = (const float*)d_in[5];
    const float* Whh0b = (const float*)d_in[6];
    const float* bih0b = (const float*)d_in[7];
    const float* bhh0b = (const float*)d_in[8];
    const float* Wih1f = (const float*)d_in[9];
    const float* Whh1f = (const float*)d_in[10];
    const float* bih1f = (const float*)d_in[11];
    const float* bhh1f = (const float*)d_in[12];
    const float* Wih1b = (const float*)d_in[13];
    const float* bih1b = (const float*)d_in[15];
    const float* bhh1b = (const float*)d_in[16];
    __hip_bfloat16* y0b = (__hip_bfloat16*)d_ws;   // [T,B,16] bf16 = 64 MiB
    float* out = (float*)d_out;

    // 8 sequences per block (8 slots x 32 lanes) -> B/8 = 512 blocks.
    hipLaunchKernelGGL(k_l0_bwd, dim3(B / 8), dim3(256), 0, stream,
                       x, Wih0b, Whh0b, bih0b, bhh0b, y0b);
    hipLaunchKernelGGL(k_fused, dim3(B / 8), dim3(256), 0, stream,
                       x, Wih0f, Whh0f, bih0f, bhh0f,
                       Wih1f, Whh1f, bih1f, bhh1f,
                       Wih1b, bih1b, bhh1b,
                       y0b, out);
}